// Round 4
// baseline (675.285 us; speedup 1.0000x reference)
//
#include <hip/hip_runtime.h>
#include <stdint.h>

typedef __attribute__((ext_vector_type(8))) __bf16 bf16x8;
typedef __attribute__((ext_vector_type(4))) float f32x4;
typedef unsigned short u16;

#define D_MODEL 1024
#define D_FF 4096
#define SEQ 2048
#define NHEAD 16
#define DH 64
#define MROWS 8192
#define LDST 72  // attn LDS row stride (elems)

__device__ __forceinline__ u16 f2bf(float f) {
  union { float f; unsigned u; } v; v.f = f;
  unsigned r = v.u + 0x7fffu + ((v.u >> 16) & 1u);
  return (u16)(r >> 16);
}

// async global->LDS, 16B per lane; lds dest wave-uniform base (+lane*16 implicit)
__device__ __forceinline__ void gload16(const u16* g, u16* l) {
  __builtin_amdgcn_global_load_lds((const __attribute__((address_space(1))) void*)(g),
                                   (__attribute__((address_space(3))) void*)(l),
                                   16, 0, 0);
}

// raw barrier (no vmcnt/lgkmcnt drain) + compiler memory fence both sides
__device__ __forceinline__ void block_bar() {
  asm volatile("" ::: "memory");
  __builtin_amdgcn_s_barrier();
  asm volatile("" ::: "memory");
}

template <int NLD>
__device__ __forceinline__ void wait_vm() {
  if constexpr (NLD == 8)      asm volatile("s_waitcnt vmcnt(8)" ::: "memory");
  else if constexpr (NLD == 6) asm volatile("s_waitcnt vmcnt(6)" ::: "memory");
  else                         asm volatile("s_waitcnt vmcnt(0)" ::: "memory");
}

// ---------------- weight f32 [K][N] -> bf16 transposed [N][K] (optional scale) ----
__global__ __launch_bounds__(256)
void wconv_kernel(const float* __restrict__ W, u16* __restrict__ Wt, int K, int N,
                  float scale) {
  __shared__ u16 t[32][33];
  const int tid = threadIdx.x, tx = tid & 31, ty = tid >> 5;
  const int n0 = blockIdx.x * 32, k0 = blockIdx.y * 32;
#pragma unroll
  for (int i = 0; i < 4; ++i) {
    int k = ty + i * 8;
    t[k][tx] = f2bf(W[(size_t)(k0 + k) * N + n0 + tx] * scale);
  }
  __syncthreads();
#pragma unroll
  for (int i = 0; i < 4; ++i) {
    int n = ty + i * 8;
    Wt[(size_t)(n0 + n) * K + k0 + tx] = t[tx][n];
  }
}

// ---------------- layernorm: f32 [row][1024] -> bf16 ----------------
__global__ __launch_bounds__(256)
void ln_kernel(const float* __restrict__ x, u16* __restrict__ out,
               const float* __restrict__ g, const float* __restrict__ beta) {
  const int row = blockIdx.x, tid = threadIdx.x;
  const float4 v = reinterpret_cast<const float4*>(x + (size_t)row * D_MODEL)[tid];
  float s = v.x + v.y + v.z + v.w;
#pragma unroll
  for (int off = 32; off; off >>= 1) s += __shfl_down(s, off);
  __shared__ float red[8];
  if ((tid & 63) == 0) red[tid >> 6] = s;
  __syncthreads();
  const float mu = (red[0] + red[1] + red[2] + red[3]) * (1.0f / D_MODEL);
  const float dx = v.x - mu, dy = v.y - mu, dz = v.z - mu, dw = v.w - mu;
  float sq = dx * dx + dy * dy + dz * dz + dw * dw;
#pragma unroll
  for (int off = 32; off; off >>= 1) sq += __shfl_down(sq, off);
  if ((tid & 63) == 0) red[4 + (tid >> 6)] = sq;
  __syncthreads();
  const float var = (red[4] + red[5] + red[6] + red[7]) * (1.0f / D_MODEL);
  const float rs = rsqrtf(var + 1e-5f);
  const float4 gv = reinterpret_cast<const float4*>(g)[tid];
  const float4 bv = reinterpret_cast<const float4*>(beta)[tid];
  ushort4 ov;
  ov.x = f2bf(dx * rs * gv.x + bv.x);
  ov.y = f2bf(dy * rs * gv.y + bv.y);
  ov.z = f2bf(dz * rs * gv.z + bv.z);
  ov.w = f2bf(dw * rs * gv.w + bv.w);
  reinterpret_cast<ushort4*>(out + (size_t)row * D_MODEL)[tid] = ov;
}

// ======== 256-wide TN GEMM, BK=64, 8 waves (2x4), 2-deep dbuf, counted vmcnt ====
// C[M,N] = A[M,K] * Bt[N,K]^T.
// EPI 1: C + bias[col] + res[idx] -> f32 outf (res may alias outf)
// EPI 2: relu(C + bias[col]) -> bf16 outb
// EPI 4: fused QKV: col segment 0 -> outb (row-major), 1 -> outb2 (row-major),
//        2 -> outb3 transposed per batch [(b*1024+c)*2048 + s]
template <int BM, int EPI>
__global__ __launch_bounds__(512, 2)
void gemm256_kernel(const u16* __restrict__ A, const u16* __restrict__ Bt,
                    int N, int K,
                    const float* __restrict__ bias,
                    const float* __restrict__ res,
                    float* __restrict__ outf, u16* __restrict__ outb,
                    u16* __restrict__ outb2, u16* __restrict__ outb3) {
  constexpr int MREP = BM / 32;       // per-wave M fragments
  constexpr int NLD = BM / 64 + 4;    // global_load_lds issues per wave per K-tile
  __shared__ __align__(16) u16 Al[2][BM * 64];
  __shared__ __align__(16) u16 Bl[2][256 * 64];
  const int tid = threadIdx.x, lane = tid & 63, wave = tid >> 6;
  const int wr = wave >> 2, wc = wave & 3;
  const int l16 = lane & 15, g8 = lane >> 4;
  const int lr = lane >> 3, lc = (lane & 7) * 8;  // staging: 8 rows x 64 elems per issue
  const int mBase = blockIdx.y * BM, nBase = blockIdx.x * 256;
  const int nt = K >> 6;

  f32x4 acc[MREP][4];
#pragma unroll
  for (int mi = 0; mi < MREP; ++mi)
#pragma unroll
    for (int nj = 0; nj < 4; ++nj) acc[mi][nj] = f32x4{0.f, 0.f, 0.f, 0.f};

  // ---- staging helper (NLD issues per wave) ----
  auto stage = [&](int k0, u16* Ad, u16* Bd) {
#pragma unroll
    for (int i = 0; i < BM / 64; ++i) {
      const int row = i * 64 + wave * 8;
      gload16(A + (size_t)(mBase + row + lr) * K + k0 + lc, Ad + row * 64);
    }
#pragma unroll
    for (int i = 0; i < 4; ++i) {
      const int row = i * 64 + wave * 8;
      gload16(Bt + (size_t)(nBase + row + lr) * K + k0 + lc, Bd + row * 64);
    }
  };

  // prologue: stage tiles 0 and 1 (nt >= 2 always here)
  stage(0, &Al[0][0], &Bl[0][0]);
  stage(64, &Al[1][0], &Bl[1][0]);
  wait_vm<NLD>();   // tile 0 landed (own); others' via barrier
  block_bar();

  for (int t = 0; t < nt; ++t) {
    const u16* Ac = &Al[t & 1][0];
    const u16* Bc = &Bl[t & 1][0];
#pragma unroll
    for (int ks = 0; ks < 2; ++ks) {
      bf16x8 af[MREP], bfr[4];
#pragma unroll
      for (int mi = 0; mi < MREP; ++mi)
        af[mi] = *reinterpret_cast<const bf16x8*>(
            &Ac[(wr * (BM / 2) + mi * 16 + l16) * 64 + ks * 32 + g8 * 8]);
#pragma unroll
      for (int nj = 0; nj < 4; ++nj)
        bfr[nj] = *reinterpret_cast<const bf16x8*>(
            &Bc[(wc * 64 + nj * 16 + l16) * 64 + ks * 32 + g8 * 8]);
#pragma unroll
      for (int mi = 0; mi < MREP; ++mi)
#pragma unroll
        for (int nj = 0; nj < 4; ++nj)
          acc[mi][nj] = __builtin_amdgcn_mfma_f32_16x16x32_bf16(af[mi], bfr[nj], acc[mi][nj], 0, 0, 0);
    }
    block_bar();                       // all waves done reading buf[t&1]
    if (t + 2 < nt) {
      stage((t + 2) * 64, &Al[t & 1][0], &Bl[t & 1][0]);  // overwrite freed buffer
      wait_vm<NLD>();                  // tile t+1's loads (own) retired
    } else {
      wait_vm<0>();                    // tail drain
    }
    if (t + 1 < nt) block_bar();       // everyone's t+1 loads visible
  }

  // ---- epilogue ----
#pragma unroll
  for (int mi = 0; mi < MREP; ++mi)
#pragma unroll
    for (int nj = 0; nj < 4; ++nj) {
      const int colB = wc * 64 + nj * 16 + l16;        // 0..255 within tile
      const int row0 = mBase + wr * (BM / 2) + mi * 16 + g8 * 4;
      if (EPI == 4) {
        const int seg = nBase >> 10;                    // 0=q 1=k 2=v
        const int c = (nBase & 1023) + colB;
        if (seg == 2) {
          const int bi = row0 >> 11, s = row0 & 2047;
          ushort4 pk;
          pk.x = f2bf(acc[mi][nj][0]);
          pk.y = f2bf(acc[mi][nj][1]);
          pk.z = f2bf(acc[mi][nj][2]);
          pk.w = f2bf(acc[mi][nj][3]);
          *reinterpret_cast<ushort4*>(outb3 + ((size_t)(bi << 10) + c) * SEQ + s) = pk;
        } else {
          u16* o = (seg == 0) ? outb : outb2;
#pragma unroll
          for (int r = 0; r < 4; ++r)
            o[(size_t)(row0 + r) * D_MODEL + c] = f2bf(acc[mi][nj][r]);
        }
      } else {
        const int col = nBase + colB;
        const float bv = bias[col];
#pragma unroll
        for (int r = 0; r < 4; ++r) {
          const size_t idx = (size_t)(row0 + r) * N + col;
          const float vv = acc[mi][nj][r];
          if (EPI == 1) {
            outf[idx] = vv + bv + res[idx];
          } else {  // EPI 2
            const float tv = vv + bv;
            outb[idx] = f2bf(tv > 0.f ? tv : 0.f);
          }
        }
      }
    }
}

// ---------------- flash attention, 4 waves x 32 q-rows, KV tile 64 ----------------
// Swapped QK^T: S^T = mfma(K_frag, Q_frag) -> lane holds q = l16, kv = kt*16+g8*4+r.
// qb pre-scaled by 1/8 (folded into wq). vb is V^T per batch: vb[(b*1024+h*64+d)*2048+s].
__global__ __launch_bounds__(256)
void attn_kernel(const u16* __restrict__ qb, const u16* __restrict__ kb,
                 const u16* __restrict__ vb, u16* __restrict__ ctx) {
  __shared__ u16 Kl[64 * LDST];
  __shared__ u16 Vl[64 * LDST];        // V^T tile: Vl[d][t]
  __shared__ u16 Pl[4][32 * LDST];     // per-wave P: [q 32][kv 64]
  const int tid = threadIdx.x;
  const int lane = tid & 63, wave = tid >> 6, g8 = lane >> 4, l16 = lane & 15;
  const int b = blockIdx.y >> 4, h = blockIdx.y & 15;
  const int q0 = blockIdx.x * 128 + wave * 32;
  const size_t rowB = (size_t)b * SEQ;
  const int colH = h * DH;
  const size_t vtBase = (size_t)(b * 1024 + colH) * SEQ;

  bf16x8 qf[2][2];
#pragma unroll
  for (int m = 0; m < 2; ++m)
#pragma unroll
    for (int ks = 0; ks < 2; ++ks)
      qf[m][ks] = *reinterpret_cast<const bf16x8*>(
          qb + (rowB + q0 + m * 16 + l16) * D_MODEL + colH + ks * 32 + g8 * 8);

  float mi[2] = {-1e30f, -1e30f}, li[2] = {0.f, 0.f};
  f32x4 o[2][4];
#pragma unroll
  for (int m = 0; m < 2; ++m)
#pragma unroll
    for (int nt = 0; nt < 4; ++nt) o[m][nt] = f32x4{0.f, 0.f, 0.f, 0.f};

  const int srow = tid >> 3, scol = (tid & 7) * 8;

  for (int t0 = 0; t0 < SEQ; t0 += 64) {
#pragma unroll
    for (int i = 0; i < 2; ++i) {
      const int row = srow + i * 32;
      *reinterpret_cast<int4*>(&Kl[row * LDST + scol]) =
          *reinterpret_cast<const int4*>(kb + (rowB + t0 + row) * D_MODEL + colH + scol);
      *reinterpret_cast<int4*>(&Vl[row * LDST + scol]) =
          *reinterpret_cast<const int4*>(vb + vtBase + (size_t)row * SEQ + t0 + scol);
    }
    __syncthreads();

    f32x4 st[2][4];
#pragma unroll
    for (int m = 0; m < 2; ++m)
#pragma unroll
      for (int kt = 0; kt < 4; ++kt) st[m][kt] = f32x4{0.f, 0.f, 0.f, 0.f};
#pragma unroll
    for (int kt = 0; kt < 4; ++kt) {
      const bf16x8 kf0 = *reinterpret_cast<const bf16x8*>(&Kl[(kt * 16 + l16) * LDST + g8 * 8]);
      const bf16x8 kf1 = *reinterpret_cast<const bf16x8*>(&Kl[(kt * 16 + l16) * LDST + 32 + g8 * 8]);
#pragma unroll
      for (int m = 0; m < 2; ++m) {
        st[m][kt] = __builtin_amdgcn_mfma_f32_16x16x32_bf16(kf0, qf[m][0], st[m][kt], 0, 0, 0);
        st[m][kt] = __builtin_amdgcn_mfma_f32_16x16x32_bf16(kf1, qf[m][1], st[m][kt], 0, 0, 0);
      }
    }

    float alpha[2];
#pragma unroll
    for (int m = 0; m < 2; ++m) {
      float pmax = st[m][0][0];
#pragma unroll
      for (int kt = 0; kt < 4; ++kt)
#pragma unroll
        for (int r = 0; r < 4; ++r) pmax = fmaxf(pmax, st[m][kt][r]);
      pmax = fmaxf(pmax, __shfl_xor(pmax, 16));
      pmax = fmaxf(pmax, __shfl_xor(pmax, 32));
      const float mnew = fmaxf(mi[m], pmax);
      alpha[m] = __expf(mi[m] - mnew);
      mi[m] = mnew;
      float sum = 0.f;
#pragma unroll
      for (int kt = 0; kt < 4; ++kt) {
        ushort4 pk;
#pragma unroll
        for (int r = 0; r < 4; ++r) {
          const float p = __expf(st[m][kt][r] - mnew);
          sum += p;
          ((u16*)&pk)[r] = f2bf(p);
        }
        *reinterpret_cast<ushort4*>(&Pl[wave][(m * 16 + l16) * LDST + kt * 16 + g8 * 4]) = pk;
      }
      sum += __shfl_xor(sum, 16);
      sum += __shfl_xor(sum, 32);
      li[m] = li[m] * alpha[m] + sum;
    }

#pragma unroll
    for (int m = 0; m < 2; ++m) {
      f32x4 al;
#pragma unroll
      for (int r = 0; r < 4; ++r) al[r] = __shfl(alpha[m], g8 * 4 + r);
#pragma unroll
      for (int nt = 0; nt < 4; ++nt) {
        f32x4 t = o[m][nt];
        t[0] *= al[0]; t[1] *= al[1]; t[2] *= al[2]; t[3] *= al[3];
        o[m][nt] = t;
      }
    }

    bf16x8 pf[2][2];
#pragma unroll
    for (int m = 0; m < 2; ++m)
#pragma unroll
      for (int ks = 0; ks < 2; ++ks)
        pf[m][ks] = *reinterpret_cast<const bf16x8*>(&Pl[wave][(m * 16 + l16) * LDST + ks * 32 + g8 * 8]);
#pragma unroll
    for (int nt = 0; nt < 4; ++nt) {
      const bf16x8 vf0 = *reinterpret_cast<const bf16x8*>(&Vl[(nt * 16 + l16) * LDST + g8 * 8]);
      const bf16x8 vf1 = *reinterpret_cast<const bf16x8*>(&Vl[(nt * 16 + l16) * LDST + 32 + g8 * 8]);
#pragma unroll
      for (int m = 0; m < 2; ++m) {
        o[m][nt] = __builtin_amdgcn_mfma_f32_16x16x32_bf16(pf[m][0], vf0, o[m][nt], 0, 0, 0);
        o[m][nt] = __builtin_amdgcn_mfma_f32_16x16x32_bf16(pf[m][1], vf1, o[m][nt], 0, 0, 0);
      }
    }
    __syncthreads();
  }

#pragma unroll
  for (int m = 0; m < 2; ++m) {
    f32x4 ld;
#pragma unroll
    for (int r = 0; r < 4; ++r) ld[r] = 1.0f / __shfl(li[m], g8 * 4 + r);
#pragma unroll
    for (int nt = 0; nt < 4; ++nt)
#pragma unroll
      for (int r = 0; r < 4; ++r) {
        const float v = o[m][nt][r] * ld[r];
        ctx[(rowB + q0 + m * 16 + g8 * 4 + r) * D_MODEL + colH + nt * 16 + l16] = f2bf(v);
      }
  }
}

extern "C" void kernel_launch(void* const* d_in, const int* in_sizes, int n_in,
                              void* d_out, int out_size, void* d_ws, size_t ws_size,
                              hipStream_t stream) {
  const float* x   = (const float*)d_in[0];
  const float* wq  = (const float*)d_in[1];
  const float* wk  = (const float*)d_in[2];
  const float* wv  = (const float*)d_in[3];
  const float* wo  = (const float*)d_in[4];
  const float* bo  = (const float*)d_in[5];
  const float* l1g = (const float*)d_in[6];
  const float* l1b = (const float*)d_in[7];
  const float* l2g = (const float*)d_in[8];
  const float* l2b = (const float*)d_in[9];
  const float* w1  = (const float*)d_in[10];
  const float* b1  = (const float*)d_in[11];
  const float* w2  = (const float*)d_in[12];
  const float* b2  = (const float*)d_in[13];
  float* outp = (float*)d_out;

  uint8_t* ws = (uint8_t*)d_ws;
  const size_t MB = 1024 * 1024;
  // workspace layout (120 MB total, lifetime-based overlays):
  u16* wqkvt = (u16*)(ws + 0 * MB);   // fused [3072][1024]: wq|wk|wv transposed
  u16* wqt   = wqkvt;
  u16* wkt   = (u16*)(ws + 2 * MB);
  u16* wvt   = (u16*)(ws + 4 * MB);
  u16* wot   = (u16*)(ws + 6 * MB);
  u16* w1t   = (u16*)(ws + 8 * MB);   // [4096][1024]
  u16* w2t   = (u16*)(ws + 16 * MB);  // [1024][4096]
  u16* xn    = (u16*)(ws + 24 * MB);  // [8192][1024]; reused as ctx after QKV
  u16* qbuf  = (u16*)(ws + 40 * MB);  // [8192][1024]; reused as h after attention
  u16* kbuf  = (u16*)(ws + 56 * MB);
  u16* vbufT = (u16*)(ws + 72 * MB);  // [4][1024][2048] transposed V
  u16* ctx   = xn;
  u16* hbuf  = qbuf;
  u16* ffh   = kbuf;                  // [8192][4096] overlays kbuf.. (vbufT dead by then)

  dim3 blk(256);
  dim3 blk5(512);

  // weights -> bf16 transposed; wq carries the 0.125 attention scale (pow2: exact)
  wconv_kernel<<<dim3(32, 32), blk, 0, stream>>>(wq, wqt, 1024, 1024, 0.125f);
  wconv_kernel<<<dim3(32, 32), blk, 0, stream>>>(wk, wkt, 1024, 1024, 1.0f);
  wconv_kernel<<<dim3(32, 32), blk, 0, stream>>>(wv, wvt, 1024, 1024, 1.0f);
  wconv_kernel<<<dim3(32, 32), blk, 0, stream>>>(wo, wot, 1024, 1024, 1.0f);
  wconv_kernel<<<dim3(128, 32), blk, 0, stream>>>(w1, w1t, 1024, 4096, 1.0f);
  wconv_kernel<<<dim3(32, 128), blk, 0, stream>>>(w2, w2t, 4096, 1024, 1.0f);

  // xn = LN1(x)
  ln_kernel<<<MROWS, blk, 0, stream>>>(x, xn, l1g, l1b);

  // fused QKV projection: [8192,1024] x [3072,1024]^T; q,k row-major, v transposed
  gemm256_kernel<256, 4><<<dim3(12, 32), blk5, 0, stream>>>(
      xn, wqkvt, 3072, 1024, nullptr, nullptr, nullptr, qbuf, kbuf, vbufT);

  // ctx = softmax(QK^T/8) V
  attn_kernel<<<dim3(16, 64), blk, 0, stream>>>(qbuf, kbuf, vbufT, ctx);

  // xt = x + ctx@wo + bo   (-> d_out, f32)
  gemm256_kernel<128, 1><<<dim3(4, 64), blk5, 0, stream>>>(
      ctx, wot, 1024, 1024, bo, x, outp, nullptr, nullptr, nullptr);

  // h = LN2(xt)
  ln_kernel<<<MROWS, blk, 0, stream>>>(outp, hbuf, l2g, l2b);

  // ffh = relu(h@w1 + b1)
  gemm256_kernel<256, 2><<<dim3(16, 32), blk5, 0, stream>>>(
      hbuf, w1t, 4096, 1024, b1, nullptr, nullptr, ffh, nullptr, nullptr);

  // out = xt + ffh@w2 + b2  (in-place on d_out)
  gemm256_kernel<128, 1><<<dim3(4, 64), blk5, 0, stream>>>(
      ffh, w2t, 1024, 4096, b2, outp, outp, nullptr, nullptr, nullptr);
}

// Round 5
// 603.507 us; speedup vs baseline: 1.1189x; 1.1189x over previous
//
#include <hip/hip_runtime.h>
#include <stdint.h>

typedef __attribute__((ext_vector_type(8))) __bf16 bf16x8;
typedef __attribute__((ext_vector_type(4))) float f32x4;
typedef unsigned short u16;

#define D_MODEL 1024
#define D_FF 4096
#define SEQ 2048
#define NHEAD 16
#define DH 64
#define MROWS 8192
#define LDST 72  // attn LDS row stride (elems)

__device__ __forceinline__ u16 f2bf(float f) {
  union { float f; unsigned u; } v; v.f = f;
  unsigned r = v.u + 0x7fffu + ((v.u >> 16) & 1u);
  return (u16)(r >> 16);
}

// async global->LDS, 16B per lane; lds dest wave-uniform base (+lane*16 implicit)
__device__ __forceinline__ void gload16(const u16* g, u16* l) {
  __builtin_amdgcn_global_load_lds((const __attribute__((address_space(1))) void*)(g),
                                   (__attribute__((address_space(3))) void*)(l),
                                   16, 0, 0);
}

// raw barrier (no vmcnt/lgkmcnt drain) + compiler memory fence both sides
__device__ __forceinline__ void block_bar() {
  asm volatile("" ::: "memory");
  __builtin_amdgcn_s_barrier();
  asm volatile("" ::: "memory");
}

template <int N>
__device__ __forceinline__ void wait_vm() {
  if constexpr (N == 6)      asm volatile("s_waitcnt vmcnt(6)" ::: "memory");
  else if constexpr (N == 4) asm volatile("s_waitcnt vmcnt(4)" ::: "memory");
  else                       asm volatile("s_waitcnt vmcnt(0)" ::: "memory");
}

// ---------------- weight f32 [K][N] -> bf16 transposed [N][K] (optional scale) ----
__global__ __launch_bounds__(256)
void wconv_kernel(const float* __restrict__ W, u16* __restrict__ Wt, int K, int N,
                  float scale) {
  __shared__ u16 t[32][33];
  const int tid = threadIdx.x, tx = tid & 31, ty = tid >> 5;
  const int n0 = blockIdx.x * 32, k0 = blockIdx.y * 32;
#pragma unroll
  for (int i = 0; i < 4; ++i) {
    int k = ty + i * 8;
    t[k][tx] = f2bf(W[(size_t)(k0 + k) * N + n0 + tx] * scale);
  }
  __syncthreads();
#pragma unroll
  for (int i = 0; i < 4; ++i) {
    int n = ty + i * 8;
    Wt[(size_t)(n0 + n) * K + k0 + tx] = t[tx][n];
  }
}

// ---------------- layernorm: f32 [row][1024] -> bf16 ----------------
__global__ __launch_bounds__(256)
void ln_kernel(const float* __restrict__ x, u16* __restrict__ out,
               const float* __restrict__ g, const float* __restrict__ beta) {
  const int row = blockIdx.x, tid = threadIdx.x;
  const float4 v = reinterpret_cast<const float4*>(x + (size_t)row * D_MODEL)[tid];
  float s = v.x + v.y + v.z + v.w;
#pragma unroll
  for (int off = 32; off; off >>= 1) s += __shfl_down(s, off);
  __shared__ float red[8];
  if ((tid & 63) == 0) red[tid >> 6] = s;
  __syncthreads();
  const float mu = (red[0] + red[1] + red[2] + red[3]) * (1.0f / D_MODEL);
  const float dx = v.x - mu, dy = v.y - mu, dz = v.z - mu, dw = v.w - mu;
  float sq = dx * dx + dy * dy + dz * dz + dw * dw;
#pragma unroll
  for (int off = 32; off; off >>= 1) sq += __shfl_down(sq, off);
  if ((tid & 63) == 0) red[4 + (tid >> 6)] = sq;
  __syncthreads();
  const float var = (red[4] + red[5] + red[6] + red[7]) * (1.0f / D_MODEL);
  const float rs = rsqrtf(var + 1e-5f);
  const float4 gv = reinterpret_cast<const float4*>(g)[tid];
  const float4 bv = reinterpret_cast<const float4*>(beta)[tid];
  ushort4 ov;
  ov.x = f2bf(dx * rs * gv.x + bv.x);
  ov.y = f2bf(dy * rs * gv.y + bv.y);
  ov.z = f2bf(dz * rs * gv.z + bv.z);
  ov.w = f2bf(dw * rs * gv.w + bv.w);
  reinterpret_cast<ushort4*>(out + (size_t)row * D_MODEL)[tid] = ov;
}

// ======== 8-phase TN GEMM (m201 template): BMx256 tile, BK=64, 8 waves (2x4) ====
// C[M,N] = A[M,K] * Bt[N,K]^T.
// LDS tiles XOR-swizzled: byte ^= (row&7)<<4 on reads; staging pre-swizzles the
// GLOBAL source column (global_load_lds writes linearly; rule: both-sides-or-neither).
// Stage chunks per K-tile per wave: A chunks rows c*64+wave*8 (c<ACH), B chunks after.
// vmcnt(VN) only at end of phases 3 and 7 (before closing barrier) -> next tile's
// DMAs confirmed behind one shared barrier; VN loads stay in flight.
// EPI 1: C + bias[col] + res[idx] -> f32 outf (res may alias outf)
// EPI 2: relu(C + bias[col]) -> bf16 outb
// EPI 4: fused QKV: col seg 0 -> outb, 1 -> outb2 (row-major), 2 -> outb3 transposed
template <int BM, int EPI>
__global__ __launch_bounds__(512, 2)
void gemm8p_kernel(const u16* __restrict__ A, const u16* __restrict__ Bt,
                   int N, int K,
                   const float* __restrict__ bias,
                   const float* __restrict__ res,
                   float* __restrict__ outf, u16* __restrict__ outb,
                   u16* __restrict__ outb2, u16* __restrict__ outb3) {
  constexpr int WM = BM / 2;          // per-wave rows
  constexpr int MREP = WM / 16;       // 8 (BM=256) or 4 (BM=128)
  constexpr int MI = MREP / 4;        // mi per phase: 2 or 1
  constexpr int ACH = BM / 64;        // A chunks per K-tile
  constexpr int VN = (BM == 256) ? 6 : 4;
  __shared__ __align__(16) u16 Al[2][BM * 64];
  __shared__ __align__(16) u16 Bl[2][256 * 64];
  const int tid = threadIdx.x, lane = tid & 63, wave = tid >> 6;
  const int wr = wave >> 2, wc = wave & 3;
  const int l16 = lane & 15, g8 = lane >> 4;
  const int srw = lane >> 3;                       // staging row within 8-row slice
  const int scl = ((lane & 7) ^ (lane >> 3)) * 8;  // pre-swizzled source col (elems)
  const int swz = (l16 & 7) << 3;                  // read-side swizzle (elems)
  const int mBase = blockIdx.y * BM, nBase = blockIdx.x * 256;
  const int nt = K >> 6;

  f32x4 acc[MREP][4];
#pragma unroll
  for (int mi = 0; mi < MREP; ++mi)
#pragma unroll
    for (int nj = 0; nj < 4; ++nj) acc[mi][nj] = f32x4{0.f, 0.f, 0.f, 0.f};

  auto stageChunk = [&](int tile, int c) {
    if (tile >= nt) return;
    const int buf = tile & 1;
    if (c < ACH) {
      const int r0 = c * 64 + wave * 8;
      gload16(A + (size_t)(mBase + r0 + srw) * K + tile * 64 + scl,
              &Al[buf][r0 * 64]);
    } else {
      const int r0 = (c - ACH) * 64 + wave * 8;
      gload16(Bt + (size_t)(nBase + r0 + srw) * K + tile * 64 + scl,
              &Bl[buf][r0 * 64]);
    }
  };

  // stage plan: per phase up to 2 (tileOffset, chunk) entries
  // BM=256: A c0-3, B c4-7.  BM=128: A c0-1, B c2-5.
  constexpr int STO256[16] = {1,1, 2,2, 2,2, 2,2, 2,2, 3,3, 3,3, 3,3};
  constexpr int STC256[16] = {1,3, 4,5, 6,7, 0,2, 1,3, 4,5, 6,7, 0,2};
  constexpr int STO128[16] = {1,1, 2,2, 2,2, 0,0, 2,2, 3,3, 3,3, 0,0};
  constexpr int STC128[16] = {0,1, 2,3, 4,5, -1,-1, 0,1, 2,3, 4,5, -1,-1};

  // prologue: tile0 fully, tile1 minus its p0-staged chunks; then confirm tile0
  constexpr int P0_256[8] = {4,5,6,7,0,2,1,3};
  constexpr int P1_256[6] = {4,5,6,7,0,2};
  constexpr int P0_128[6] = {2,3,4,5,0,1};
  constexpr int P1_128[4] = {2,3,4,5};
  if constexpr (BM == 256) {
#pragma unroll
    for (int i = 0; i < 8; ++i) stageChunk(0, P0_256[i]);
#pragma unroll
    for (int i = 0; i < 6; ++i) stageChunk(1, P1_256[i]);
  } else {
#pragma unroll
    for (int i = 0; i < 6; ++i) stageChunk(0, P0_128[i]);
#pragma unroll
    for (int i = 0; i < 4; ++i) stageChunk(1, P1_128[i]);
  }
  wait_vm<VN>();
  block_bar();

  for (int T = 0; T < nt; T += 2) {   // T even -> buf of tile T+(p>>2) is p>>2
    bf16x8 bfr[4][2];
#pragma unroll
    for (int p = 0; p < 8; ++p) {
      const int q = p & 3;
      const int buf = p >> 2;
      // ---- ds-reads for this phase ----
      if (q == 0) {
#pragma unroll
        for (int nj = 0; nj < 4; ++nj)
#pragma unroll
          for (int ks = 0; ks < 2; ++ks) {
            const int rb = wc * 64 + nj * 16 + l16;
            bfr[nj][ks] = *reinterpret_cast<const bf16x8*>(
                &Bl[buf][rb * 64 + ((ks * 32 + g8 * 8) ^ swz)]);
          }
      }
      bf16x8 af[MI][2];
#pragma unroll
      for (int i = 0; i < MI; ++i)
#pragma unroll
        for (int ks = 0; ks < 2; ++ks) {
          const int ra = wr * WM + (q * MI + i) * 16 + l16;
          af[i][ks] = *reinterpret_cast<const bf16x8*>(
              &Al[buf][ra * 64 + ((ks * 32 + g8 * 8) ^ swz)]);
        }
      // ---- stage prefetch (2 issues) ----
      if constexpr (BM == 256) {
        stageChunk(T + STO256[2 * p], STC256[2 * p]);
        stageChunk(T + STO256[2 * p + 1], STC256[2 * p + 1]);
      } else {
        if (STC128[2 * p] >= 0) {
          stageChunk(T + STO128[2 * p], STC128[2 * p]);
          stageChunk(T + STO128[2 * p + 1], STC128[2 * p + 1]);
        }
      }
      block_bar();
      // ---- MFMA cluster ----
      __builtin_amdgcn_s_setprio(1);
#pragma unroll
      for (int i = 0; i < MI; ++i)
#pragma unroll
        for (int nj = 0; nj < 4; ++nj)
#pragma unroll
          for (int ks = 0; ks < 2; ++ks)
            acc[q * MI + i][nj] = __builtin_amdgcn_mfma_f32_16x16x32_bf16(
                af[i][ks], bfr[nj][ks], acc[q * MI + i][nj], 0, 0, 0);
      __builtin_amdgcn_s_setprio(0);
      // ---- counted waits at phase 3 / phase 7 end (before closing barrier) ----
      if (p == 3) {
        if (T + 2 < nt) wait_vm<VN>(); else wait_vm<0>();
      } else if (p == 7) {
        wait_vm<VN>();
      }
      block_bar();
    }
  }

  // ---- epilogue ----
#pragma unroll
  for (int mi = 0; mi < MREP; ++mi)
#pragma unroll
    for (int nj = 0; nj < 4; ++nj) {
      const int colB = wc * 64 + nj * 16 + l16;
      const int row0 = mBase + wr * WM + mi * 16 + g8 * 4;
      if (EPI == 4) {
        const int seg = nBase >> 10;                 // 0=q 1=k 2=v
        const int c = (nBase & 1023) + colB;
        if (seg == 2) {
          const int bi = row0 >> 11, s = row0 & 2047;
          ushort4 pk;
          pk.x = f2bf(acc[mi][nj][0]);
          pk.y = f2bf(acc[mi][nj][1]);
          pk.z = f2bf(acc[mi][nj][2]);
          pk.w = f2bf(acc[mi][nj][3]);
          *reinterpret_cast<ushort4*>(outb3 + ((size_t)(bi << 10) + c) * SEQ + s) = pk;
        } else {
          u16* o = (seg == 0) ? outb : outb2;
#pragma unroll
          for (int r = 0; r < 4; ++r)
            o[(size_t)(row0 + r) * D_MODEL + c] = f2bf(acc[mi][nj][r]);
        }
      } else {
        const int col = nBase + colB;
        const float bv = bias[col];
#pragma unroll
        for (int r = 0; r < 4; ++r) {
          const size_t idx = (size_t)(row0 + r) * N + col;
          const float vv = acc[mi][nj][r];
          if (EPI == 1) {
            outf[idx] = vv + bv + res[idx];
          } else {  // EPI 2
            const float tv = vv + bv;
            outb[idx] = f2bf(tv > 0.f ? tv : 0.f);
          }
        }
      }
    }
}

// ---------------- flash attention, 4 waves x 32 q-rows, KV tile 64 ----------------
// Swapped QK^T: S^T = mfma(K_frag, Q_frag) -> lane holds q = l16, kv = kt*16+g8*4+r.
// qb pre-scaled by 1/8 (folded into wq). vb is V^T per batch: vb[(b*1024+h*64+d)*2048+s].
__global__ __launch_bounds__(256)
void attn_kernel(const u16* __restrict__ qb, const u16* __restrict__ kb,
                 const u16* __restrict__ vb, u16* __restrict__ ctx) {
  __shared__ u16 Kl[64 * LDST];
  __shared__ u16 Vl[64 * LDST];        // V^T tile: Vl[d][t]
  __shared__ u16 Pl[4][32 * LDST];     // per-wave P: [q 32][kv 64]
  const int tid = threadIdx.x;
  const int lane = tid & 63, wave = tid >> 6, g8 = lane >> 4, l16 = lane & 15;
  const int b = blockIdx.y >> 4, h = blockIdx.y & 15;
  const int q0 = blockIdx.x * 128 + wave * 32;
  const size_t rowB = (size_t)b * SEQ;
  const int colH = h * DH;
  const size_t vtBase = (size_t)(b * 1024 + colH) * SEQ;

  bf16x8 qf[2][2];
#pragma unroll
  for (int m = 0; m < 2; ++m)
#pragma unroll
    for (int ks = 0; ks < 2; ++ks)
      qf[m][ks] = *reinterpret_cast<const bf16x8*>(
          qb + (rowB + q0 + m * 16 + l16) * D_MODEL + colH + ks * 32 + g8 * 8);

  float mi[2] = {-1e30f, -1e30f}, li[2] = {0.f, 0.f};
  f32x4 o[2][4];
#pragma unroll
  for (int m = 0; m < 2; ++m)
#pragma unroll
    for (int nt = 0; nt < 4; ++nt) o[m][nt] = f32x4{0.f, 0.f, 0.f, 0.f};

  const int srow = tid >> 3, scol = (tid & 7) * 8;

  for (int t0 = 0; t0 < SEQ; t0 += 64) {
#pragma unroll
    for (int i = 0; i < 2; ++i) {
      const int row = srow + i * 32;
      *reinterpret_cast<int4*>(&Kl[row * LDST + scol]) =
          *reinterpret_cast<const int4*>(kb + (rowB + t0 + row) * D_MODEL + colH + scol);
      *reinterpret_cast<int4*>(&Vl[row * LDST + scol]) =
          *reinterpret_cast<const int4*>(vb + vtBase + (size_t)row * SEQ + t0 + scol);
    }
    __syncthreads();

    f32x4 st[2][4];
#pragma unroll
    for (int m = 0; m < 2; ++m)
#pragma unroll
      for (int kt = 0; kt < 4; ++kt) st[m][kt] = f32x4{0.f, 0.f, 0.f, 0.f};
#pragma unroll
    for (int kt = 0; kt < 4; ++kt) {
      const bf16x8 kf0 = *reinterpret_cast<const bf16x8*>(&Kl[(kt * 16 + l16) * LDST + g8 * 8]);
      const bf16x8 kf1 = *reinterpret_cast<const bf16x8*>(&Kl[(kt * 16 + l16) * LDST + 32 + g8 * 8]);
#pragma unroll
      for (int m = 0; m < 2; ++m) {
        st[m][kt] = __builtin_amdgcn_mfma_f32_16x16x32_bf16(kf0, qf[m][0], st[m][kt], 0, 0, 0);
        st[m][kt] = __builtin_amdgcn_mfma_f32_16x16x32_bf16(kf1, qf[m][1], st[m][kt], 0, 0, 0);
      }
    }

    float alpha[2];
#pragma unroll
    for (int m = 0; m < 2; ++m) {
      float pmax = st[m][0][0];
#pragma unroll
      for (int kt = 0; kt < 4; ++kt)
#pragma unroll
        for (int r = 0; r < 4; ++r) pmax = fmaxf(pmax, st[m][kt][r]);
      pmax = fmaxf(pmax, __shfl_xor(pmax, 16));
      pmax = fmaxf(pmax, __shfl_xor(pmax, 32));
      const float mnew = fmaxf(mi[m], pmax);
      alpha[m] = __expf(mi[m] - mnew);
      mi[m] = mnew;
      float sum = 0.f;
#pragma unroll
      for (int kt = 0; kt < 4; ++kt) {
        ushort4 pk;
#pragma unroll
        for (int r = 0; r < 4; ++r) {
          const float p = __expf(st[m][kt][r] - mnew);
          sum += p;
          ((u16*)&pk)[r] = f2bf(p);
        }
        *reinterpret_cast<ushort4*>(&Pl[wave][(m * 16 + l16) * LDST + kt * 16 + g8 * 4]) = pk;
      }
      sum += __shfl_xor(sum, 16);
      sum += __shfl_xor(sum, 32);
      li[m] = li[m] * alpha[m] + sum;
    }

#pragma unroll
    for (int m = 0; m < 2; ++m) {
      f32x4 al;
#pragma unroll
      for (int r = 0; r < 4; ++r) al[r] = __shfl(alpha[m], g8 * 4 + r);
#pragma unroll
      for (int nt = 0; nt < 4; ++nt) {
        f32x4 t = o[m][nt];
        t[0] *= al[0]; t[1] *= al[1]; t[2] *= al[2]; t[3] *= al[3];
        o[m][nt] = t;
      }
    }

    bf16x8 pf[2][2];
#pragma unroll
    for (int m = 0; m < 2; ++m)
#pragma unroll
      for (int ks = 0; ks < 2; ++ks)
        pf[m][ks] = *reinterpret_cast<const bf16x8*>(&Pl[wave][(m * 16 + l16) * LDST + ks * 32 + g8 * 8]);
#pragma unroll
    for (int nt = 0; nt < 4; ++nt) {
      const bf16x8 vf0 = *reinterpret_cast<const bf16x8*>(&Vl[(nt * 16 + l16) * LDST + g8 * 8]);
      const bf16x8 vf1 = *reinterpret_cast<const bf16x8*>(&Vl[(nt * 16 + l16) * LDST + 32 + g8 * 8]);
#pragma unroll
      for (int m = 0; m < 2; ++m) {
        o[m][nt] = __builtin_amdgcn_mfma_f32_16x16x32_bf16(pf[m][0], vf0, o[m][nt], 0, 0, 0);
        o[m][nt] = __builtin_amdgcn_mfma_f32_16x16x32_bf16(pf[m][1], vf1, o[m][nt], 0, 0, 0);
      }
    }
    __syncthreads();
  }

#pragma unroll
  for (int m = 0; m < 2; ++m) {
    f32x4 ld;
#pragma unroll
    for (int r = 0; r < 4; ++r) ld[r] = 1.0f / __shfl(li[m], g8 * 4 + r);
#pragma unroll
    for (int nt = 0; nt < 4; ++nt)
#pragma unroll
      for (int r = 0; r < 4; ++r) {
        const float v = o[m][nt][r] * ld[r];
        ctx[(rowB + q0 + m * 16 + g8 * 4 + r) * D_MODEL + colH + nt * 16 + l16] = f2bf(v);
      }
  }
}

extern "C" void kernel_launch(void* const* d_in, const int* in_sizes, int n_in,
                              void* d_out, int out_size, void* d_ws, size_t ws_size,
                              hipStream_t stream) {
  const float* x   = (const float*)d_in[0];
  const float* wq  = (const float*)d_in[1];
  const float* wk  = (const float*)d_in[2];
  const float* wv  = (const float*)d_in[3];
  const float* wo  = (const float*)d_in[4];
  const float* bo  = (const float*)d_in[5];
  const float* l1g = (const float*)d_in[6];
  const float* l1b = (const float*)d_in[7];
  const float* l2g = (const float*)d_in[8];
  const float* l2b = (const float*)d_in[9];
  const float* w1  = (const float*)d_in[10];
  const float* b1  = (const float*)d_in[11];
  const float* w2  = (const float*)d_in[12];
  const float* b2  = (const float*)d_in[13];
  float* outp = (float*)d_out;

  uint8_t* ws = (uint8_t*)d_ws;
  const size_t MB = 1024 * 1024;
  // workspace layout (120 MB total, lifetime-based overlays):
  u16* wqkvt = (u16*)(ws + 0 * MB);   // fused [3072][1024]: wq|wk|wv transposed
  u16* wqt   = wqkvt;
  u16* wkt   = (u16*)(ws + 2 * MB);
  u16* wvt   = (u16*)(ws + 4 * MB);
  u16* wot   = (u16*)(ws + 6 * MB);
  u16* w1t   = (u16*)(ws + 8 * MB);   // [4096][1024]
  u16* w2t   = (u16*)(ws + 16 * MB);  // [1024][4096]
  u16* xn    = (u16*)(ws + 24 * MB);  // [8192][1024]; reused as ctx after QKV
  u16* qbuf  = (u16*)(ws + 40 * MB);  // [8192][1024]; reused as h after attention
  u16* kbuf  = (u16*)(ws + 56 * MB);
  u16* vbufT = (u16*)(ws + 72 * MB);  // [4][1024][2048] transposed V
  u16* ctx   = xn;
  u16* hbuf  = qbuf;
  u16* ffh   = kbuf;                  // [8192][4096] overlays kbuf.. (vbufT dead by then)

  dim3 blk(256);
  dim3 blk5(512);

  // weights -> bf16 transposed; wq carries the 0.125 attention scale (pow2: exact)
  wconv_kernel<<<dim3(32, 32), blk, 0, stream>>>(wq, wqt, 1024, 1024, 0.125f);
  wconv_kernel<<<dim3(32, 32), blk, 0, stream>>>(wk, wkt, 1024, 1024, 1.0f);
  wconv_kernel<<<dim3(32, 32), blk, 0, stream>>>(wv, wvt, 1024, 1024, 1.0f);
  wconv_kernel<<<dim3(32, 32), blk, 0, stream>>>(wo, wot, 1024, 1024, 1.0f);
  wconv_kernel<<<dim3(128, 32), blk, 0, stream>>>(w1, w1t, 1024, 4096, 1.0f);
  wconv_kernel<<<dim3(32, 128), blk, 0, stream>>>(w2, w2t, 4096, 1024, 1.0f);

  // xn = LN1(x)
  ln_kernel<<<MROWS, blk, 0, stream>>>(x, xn, l1g, l1b);

  // fused QKV projection: [8192,1024] x [3072,1024]^T; q,k row-major, v transposed
  gemm8p_kernel<128, 4><<<dim3(12, 64), blk5, 0, stream>>>(
      xn, wqkvt, 3072, 1024, nullptr, nullptr, nullptr, qbuf, kbuf, vbufT);

  // ctx = softmax(QK^T/8) V
  attn_kernel<<<dim3(16, 64), blk, 0, stream>>>(qbuf, kbuf, vbufT, ctx);

  // xt = x + ctx@wo + bo   (-> d_out, f32)
  gemm8p_kernel<128, 1><<<dim3(4, 64), blk5, 0, stream>>>(
      ctx, wot, 1024, 1024, bo, x, outp, nullptr, nullptr, nullptr);

  // h = LN2(xt)
  ln_kernel<<<MROWS, blk, 0, stream>>>(outp, hbuf, l2g, l2b);

  // ffh = relu(h@w1 + b1)
  gemm8p_kernel<256, 2><<<dim3(16, 32), blk5, 0, stream>>>(
      hbuf, w1t, 4096, 1024, b1, nullptr, nullptr, ffh, nullptr, nullptr);

  // out = xt + ffh@w2 + b2  (in-place on d_out)
  gemm8p_kernel<128, 1><<<dim3(4, 64), blk5, 0, stream>>>(
      ffh, w2t, 1024, 4096, b2, outp, outp, nullptr, nullptr, nullptr);
}

// Round 6
// 553.239 us; speedup vs baseline: 1.2206x; 1.0909x over previous
//
#include <hip/hip_runtime.h>
#include <stdint.h>

typedef __attribute__((ext_vector_type(8))) __bf16 bf16x8;
typedef __attribute__((ext_vector_type(4))) __bf16 bf16x4;
typedef __attribute__((ext_vector_type(4))) float f32x4;
typedef unsigned short u16;

#define D_MODEL 1024
#define D_FF 4096
#define SEQ 2048
#define NHEAD 16
#define DH 64
#define MROWS 8192

__device__ __forceinline__ u16 f2bf(float f) {
  union { float f; unsigned u; } v; v.f = f;
  unsigned r = v.u + 0x7fffu + ((v.u >> 16) & 1u);
  return (u16)(r >> 16);
}

// async global->LDS, 16B per lane; lds dest wave-uniform base (+lane*16 implicit)
__device__ __forceinline__ void gload16(const u16* g, u16* l) {
  __builtin_amdgcn_global_load_lds((const __attribute__((address_space(1))) void*)(g),
                                   (__attribute__((address_space(3))) void*)(l),
                                   16, 0, 0);
}

// raw barrier (no vmcnt/lgkmcnt drain) + compiler memory fence both sides
__device__ __forceinline__ void block_bar() {
  asm volatile("" ::: "memory");
  __builtin_amdgcn_s_barrier();
  asm volatile("" ::: "memory");
}

template <int N>
__device__ __forceinline__ void wait_vm() {
  if constexpr (N == 6)      asm volatile("s_waitcnt vmcnt(6)" ::: "memory");
  else if constexpr (N == 4) asm volatile("s_waitcnt vmcnt(4)" ::: "memory");
  else                       asm volatile("s_waitcnt vmcnt(0)" ::: "memory");
}

// ---------------- weight f32 [K][N] -> bf16 transposed [N][K] (optional scale) ----
__global__ __launch_bounds__(256)
void wconv_kernel(const float* __restrict__ W, u16* __restrict__ Wt, int K, int N,
                  float scale) {
  __shared__ u16 t[32][33];
  const int tid = threadIdx.x, tx = tid & 31, ty = tid >> 5;
  const int n0 = blockIdx.x * 32, k0 = blockIdx.y * 32;
#pragma unroll
  for (int i = 0; i < 4; ++i) {
    int k = ty + i * 8;
    t[k][tx] = f2bf(W[(size_t)(k0 + k) * N + n0 + tx] * scale);
  }
  __syncthreads();
#pragma unroll
  for (int i = 0; i < 4; ++i) {
    int n = ty + i * 8;
    Wt[(size_t)(n0 + n) * K + k0 + tx] = t[tx][n];
  }
}

// ---------------- layernorm: f32 [row][1024] -> bf16 ----------------
__global__ __launch_bounds__(256)
void ln_kernel(const float* __restrict__ x, u16* __restrict__ out,
               const float* __restrict__ g, const float* __restrict__ beta) {
  const int row = blockIdx.x, tid = threadIdx.x;
  const float4 v = reinterpret_cast<const float4*>(x + (size_t)row * D_MODEL)[tid];
  float s = v.x + v.y + v.z + v.w;
#pragma unroll
  for (int off = 32; off; off >>= 1) s += __shfl_down(s, off);
  __shared__ float red[8];
  if ((tid & 63) == 0) red[tid >> 6] = s;
  __syncthreads();
  const float mu = (red[0] + red[1] + red[2] + red[3]) * (1.0f / D_MODEL);
  const float dx = v.x - mu, dy = v.y - mu, dz = v.z - mu, dw = v.w - mu;
  float sq = dx * dx + dy * dy + dz * dz + dw * dw;
#pragma unroll
  for (int off = 32; off; off >>= 1) sq += __shfl_down(sq, off);
  if ((tid & 63) == 0) red[4 + (tid >> 6)] = sq;
  __syncthreads();
  const float var = (red[4] + red[5] + red[6] + red[7]) * (1.0f / D_MODEL);
  const float rs = rsqrtf(var + 1e-5f);
  const float4 gv = reinterpret_cast<const float4*>(g)[tid];
  const float4 bv = reinterpret_cast<const float4*>(beta)[tid];
  ushort4 ov;
  ov.x = f2bf(dx * rs * gv.x + bv.x);
  ov.y = f2bf(dy * rs * gv.y + bv.y);
  ov.z = f2bf(dz * rs * gv.z + bv.z);
  ov.w = f2bf(dw * rs * gv.w + bv.w);
  reinterpret_cast<ushort4*>(out + (size_t)row * D_MODEL)[tid] = ov;
}

// ======== 8-phase TN GEMM (m201 template): BMx256 tile, BK=64, 8 waves (2x4) ====
// (unchanged from round 5 — verified + won)
template <int BM, int EPI>
__global__ __launch_bounds__(512, 2)
void gemm8p_kernel(const u16* __restrict__ A, const u16* __restrict__ Bt,
                   int N, int K,
                   const float* __restrict__ bias,
                   const float* __restrict__ res,
                   float* __restrict__ outf, u16* __restrict__ outb,
                   u16* __restrict__ outb2, u16* __restrict__ outb3) {
  constexpr int WM = BM / 2;
  constexpr int MREP = WM / 16;
  constexpr int MI = MREP / 4;
  constexpr int ACH = BM / 64;
  constexpr int VN = (BM == 256) ? 6 : 4;
  __shared__ __align__(16) u16 Al[2][BM * 64];
  __shared__ __align__(16) u16 Bl[2][256 * 64];
  const int tid = threadIdx.x, lane = tid & 63, wave = tid >> 6;
  const int wr = wave >> 2, wc = wave & 3;
  const int l16 = lane & 15, g8 = lane >> 4;
  const int srw = lane >> 3;
  const int scl = ((lane & 7) ^ (lane >> 3)) * 8;
  const int swz = (l16 & 7) << 3;
  const int mBase = blockIdx.y * BM, nBase = blockIdx.x * 256;
  const int nt = K >> 6;

  f32x4 acc[MREP][4];
#pragma unroll
  for (int mi = 0; mi < MREP; ++mi)
#pragma unroll
    for (int nj = 0; nj < 4; ++nj) acc[mi][nj] = f32x4{0.f, 0.f, 0.f, 0.f};

  auto stageChunk = [&](int tile, int c) {
    if (tile >= nt) return;
    const int buf = tile & 1;
    if (c < ACH) {
      const int r0 = c * 64 + wave * 8;
      gload16(A + (size_t)(mBase + r0 + srw) * K + tile * 64 + scl,
              &Al[buf][r0 * 64]);
    } else {
      const int r0 = (c - ACH) * 64 + wave * 8;
      gload16(Bt + (size_t)(nBase + r0 + srw) * K + tile * 64 + scl,
              &Bl[buf][r0 * 64]);
    }
  };

  constexpr int STO256[16] = {1,1, 2,2, 2,2, 2,2, 2,2, 3,3, 3,3, 3,3};
  constexpr int STC256[16] = {1,3, 4,5, 6,7, 0,2, 1,3, 4,5, 6,7, 0,2};
  constexpr int STO128[16] = {1,1, 2,2, 2,2, 0,0, 2,2, 3,3, 3,3, 0,0};
  constexpr int STC128[16] = {0,1, 2,3, 4,5, -1,-1, 0,1, 2,3, 4,5, -1,-1};

  constexpr int P0_256[8] = {4,5,6,7,0,2,1,3};
  constexpr int P1_256[6] = {4,5,6,7,0,2};
  constexpr int P0_128[6] = {2,3,4,5,0,1};
  constexpr int P1_128[4] = {2,3,4,5};
  if constexpr (BM == 256) {
#pragma unroll
    for (int i = 0; i < 8; ++i) stageChunk(0, P0_256[i]);
#pragma unroll
    for (int i = 0; i < 6; ++i) stageChunk(1, P1_256[i]);
  } else {
#pragma unroll
    for (int i = 0; i < 6; ++i) stageChunk(0, P0_128[i]);
#pragma unroll
    for (int i = 0; i < 4; ++i) stageChunk(1, P1_128[i]);
  }
  wait_vm<VN>();
  block_bar();

  for (int T = 0; T < nt; T += 2) {
    bf16x8 bfr[4][2];
#pragma unroll
    for (int p = 0; p < 8; ++p) {
      const int q = p & 3;
      const int buf = p >> 2;
      if (q == 0) {
#pragma unroll
        for (int nj = 0; nj < 4; ++nj)
#pragma unroll
          for (int ks = 0; ks < 2; ++ks) {
            const int rb = wc * 64 + nj * 16 + l16;
            bfr[nj][ks] = *reinterpret_cast<const bf16x8*>(
                &Bl[buf][rb * 64 + ((ks * 32 + g8 * 8) ^ swz)]);
          }
      }
      bf16x8 af[MI][2];
#pragma unroll
      for (int i = 0; i < MI; ++i)
#pragma unroll
        for (int ks = 0; ks < 2; ++ks) {
          const int ra = wr * WM + (q * MI + i) * 16 + l16;
          af[i][ks] = *reinterpret_cast<const bf16x8*>(
              &Al[buf][ra * 64 + ((ks * 32 + g8 * 8) ^ swz)]);
        }
      if constexpr (BM == 256) {
        stageChunk(T + STO256[2 * p], STC256[2 * p]);
        stageChunk(T + STO256[2 * p + 1], STC256[2 * p + 1]);
      } else {
        if (STC128[2 * p] >= 0) {
          stageChunk(T + STO128[2 * p], STC128[2 * p]);
          stageChunk(T + STO128[2 * p + 1], STC128[2 * p + 1]);
        }
      }
      block_bar();
      __builtin_amdgcn_s_setprio(1);
#pragma unroll
      for (int i = 0; i < MI; ++i)
#pragma unroll
        for (int nj = 0; nj < 4; ++nj)
#pragma unroll
          for (int ks = 0; ks < 2; ++ks)
            acc[q * MI + i][nj] = __builtin_amdgcn_mfma_f32_16x16x32_bf16(
                af[i][ks], bfr[nj][ks], acc[q * MI + i][nj], 0, 0, 0);
      __builtin_amdgcn_s_setprio(0);
      if (p == 3) {
        if (T + 2 < nt) wait_vm<VN>(); else wait_vm<0>();
      } else if (p == 7) {
        wait_vm<VN>();
      }
      block_bar();
    }
  }

#pragma unroll
  for (int mi = 0; mi < MREP; ++mi)
#pragma unroll
    for (int nj = 0; nj < 4; ++nj) {
      const int colB = wc * 64 + nj * 16 + l16;
      const int row0 = mBase + wr * WM + mi * 16 + g8 * 4;
      if (EPI == 4) {
        const int seg = nBase >> 10;
        const int c = (nBase & 1023) + colB;
        if (seg == 2) {
          const int bi = row0 >> 11, s = row0 & 2047;
          ushort4 pk;
          pk.x = f2bf(acc[mi][nj][0]);
          pk.y = f2bf(acc[mi][nj][1]);
          pk.z = f2bf(acc[mi][nj][2]);
          pk.w = f2bf(acc[mi][nj][3]);
          *reinterpret_cast<ushort4*>(outb3 + ((size_t)(bi << 10) + c) * SEQ + s) = pk;
        } else {
          u16* o = (seg == 0) ? outb : outb2;
#pragma unroll
          for (int r = 0; r < 4; ++r)
            o[(size_t)(row0 + r) * D_MODEL + c] = f2bf(acc[mi][nj][r]);
        }
      } else {
        const int col = nBase + colB;
        const float bv = bias[col];
#pragma unroll
        for (int r = 0; r < 4; ++r) {
          const size_t idx = (size_t)(row0 + r) * N + col;
          const float vv = acc[mi][nj][r];
          if (EPI == 1) {
            outf[idx] = vv + bv + res[idx];
          } else {
            const float tv = vv + bv;
            outb[idx] = f2bf(tv > 0.f ? tv : 0.f);
          }
        }
      }
    }
}

// ---------------- flash attention v3: async dbuf KV, exp2, native casts ----------
// 4 waves x 32 q-rows, KV tile 64. Swapped QK^T: lane holds q = l16, kv = kt*16+g8*4+r.
// qb pre-scaled by 0.125*log2(e) (folded into wq) -> softmax uses exp2 directly.
// K/V staged via global_load_lds with pre-swizzled SOURCE col; all LDS reads/writes
// XOR-swizzled (elem_col ^= (row&7)*8) -> ~2-way conflicts. One raw barrier per tile;
// next tile's DMA issued before compute, vmcnt(0) just before the barrier.
// vb is V^T per batch: vb[(b*1024 + h*64 + d)*2048 + s].
__global__ __launch_bounds__(256)
void attn_kernel(const u16* __restrict__ qb, const u16* __restrict__ kb,
                 const u16* __restrict__ vb, u16* __restrict__ ctx) {
  __shared__ __align__(16) u16 Kl[2][64 * 64];
  __shared__ __align__(16) u16 Vl[2][64 * 64];   // V^T tile: Vl[d][t]
  __shared__ __align__(16) u16 Pl[4][32 * 64];   // per-wave P: [q 32][kv 64]
  const int tid = threadIdx.x;
  const int lane = tid & 63, wave = tid >> 6, g8 = lane >> 4, l16 = lane & 15;
  const int b = blockIdx.y >> 4, h = blockIdx.y & 15;
  const int q0 = blockIdx.x * 128 + wave * 32;
  const size_t rowB = (size_t)b * SEQ;
  const int colH = h * DH;
  const size_t vtBase = (size_t)(b * 1024 + colH) * SEQ;
  const int srw = lane >> 3;                       // staging row within 8-row slice
  const int scl = ((lane & 7) ^ (lane >> 3)) * 8;  // pre-swizzled source col (elems)
  const int cswz = (l16 & 7) * 8;                  // read-side swizzle (elems)

  bf16x8 qf[2][2];
#pragma unroll
  for (int m = 0; m < 2; ++m)
#pragma unroll
    for (int ks = 0; ks < 2; ++ks)
      qf[m][ks] = *reinterpret_cast<const bf16x8*>(
          qb + (rowB + q0 + m * 16 + l16) * D_MODEL + colH + ks * 32 + g8 * 8);

  float mi[2] = {-1e30f, -1e30f}, li[2] = {0.f, 0.f};
  f32x4 o[2][4];
#pragma unroll
  for (int m = 0; m < 2; ++m)
#pragma unroll
    for (int nt = 0; nt < 4; ++nt) o[m][nt] = f32x4{0.f, 0.f, 0.f, 0.f};

  // stage KV tile t0 into buffer buf (2 K + 2 V issues per wave)
  auto stageKV = [&](int t0, int buf) {
    if (t0 >= SEQ) return;
#pragma unroll
    for (int i = 0; i < 2; ++i) {
      const int r0 = wave * 16 + i * 8;
      gload16(kb + (rowB + t0 + r0 + srw) * D_MODEL + colH + scl, &Kl[buf][r0 * 64]);
      gload16(vb + vtBase + (size_t)(r0 + srw) * SEQ + t0 + scl, &Vl[buf][r0 * 64]);
    }
  };

  stageKV(0, 0);
  wait_vm<0>();
  block_bar();

  int buf = 0;
  for (int t0 = 0; t0 < SEQ; t0 += 64, buf ^= 1) {
    // prefetch next tile into the other buffer (landing checked at end-of-tile barrier)
    stageKV(t0 + 64, buf ^ 1);

    // S^T tiles: st[m][kt], rows kv = kt*16+g8*4+r, cols q = m*16+l16
    f32x4 st[2][4];
#pragma unroll
    for (int m = 0; m < 2; ++m)
#pragma unroll
      for (int kt = 0; kt < 4; ++kt) st[m][kt] = f32x4{0.f, 0.f, 0.f, 0.f};
#pragma unroll
    for (int kt = 0; kt < 4; ++kt) {
      const bf16x8 kf0 = *reinterpret_cast<const bf16x8*>(
          &Kl[buf][(kt * 16 + l16) * 64 + ((g8 * 8) ^ cswz)]);
      const bf16x8 kf1 = *reinterpret_cast<const bf16x8*>(
          &Kl[buf][(kt * 16 + l16) * 64 + ((32 + g8 * 8) ^ cswz)]);
#pragma unroll
      for (int m = 0; m < 2; ++m) {
        st[m][kt] = __builtin_amdgcn_mfma_f32_16x16x32_bf16(kf0, qf[m][0], st[m][kt], 0, 0, 0);
        st[m][kt] = __builtin_amdgcn_mfma_f32_16x16x32_bf16(kf1, qf[m][1], st[m][kt], 0, 0, 0);
      }
    }

    float alpha[2];
#pragma unroll
    for (int m = 0; m < 2; ++m) {
      float pmax = st[m][0][0];
#pragma unroll
      for (int kt = 0; kt < 4; ++kt)
#pragma unroll
        for (int r = 0; r < 4; ++r) pmax = fmaxf(pmax, st[m][kt][r]);
      pmax = fmaxf(pmax, __shfl_xor(pmax, 16));
      pmax = fmaxf(pmax, __shfl_xor(pmax, 32));
      const float mnew = fmaxf(mi[m], pmax);
      alpha[m] = __builtin_amdgcn_exp2f(mi[m] - mnew);
      mi[m] = mnew;
      float sum = 0.f;
#pragma unroll
      for (int kt = 0; kt < 4; ++kt) {
        bf16x4 pk;
#pragma unroll
        for (int r = 0; r < 4; ++r) {
          const float p = __builtin_amdgcn_exp2f(st[m][kt][r] - mnew);
          sum += p;
          pk[r] = (__bf16)p;   // compiler packs pairs via v_cvt_pk_bf16_f32
        }
        const int row = m * 16 + l16;
        *reinterpret_cast<bf16x4*>(
            &Pl[wave][row * 64 + ((kt * 16 + g8 * 4) ^ cswz)]) = pk;
      }
      sum += __shfl_xor(sum, 16);
      sum += __shfl_xor(sum, 32);
      li[m] = li[m] * alpha[m] + sum;
    }

    // rescale o: alpha needed at q = g8*4+r -> broadcast from lane g8*4+r
#pragma unroll
    for (int m = 0; m < 2; ++m) {
      f32x4 al;
#pragma unroll
      for (int r = 0; r < 4; ++r) al[r] = __shfl(alpha[m], g8 * 4 + r);
#pragma unroll
      for (int nt = 0; nt < 4; ++nt) {
        f32x4 t = o[m][nt];
        t[0] *= al[0]; t[1] *= al[1]; t[2] *= al[2]; t[3] *= al[3];
        o[m][nt] = t;
      }
    }

    // O += P V  (P A-frags from per-wave LDS; V^T B-frags, all swizzled reads)
    bf16x8 pf[2][2];
#pragma unroll
    for (int m = 0; m < 2; ++m)
#pragma unroll
      for (int ks = 0; ks < 2; ++ks)
        pf[m][ks] = *reinterpret_cast<const bf16x8*>(
            &Pl[wave][(m * 16 + l16) * 64 + ((ks * 32 + g8 * 8) ^ cswz)]);
#pragma unroll
    for (int nt = 0; nt < 4; ++nt) {
      const bf16x8 vf0 = *reinterpret_cast<const bf16x8*>(
          &Vl[buf][(nt * 16 + l16) * 64 + ((g8 * 8) ^ cswz)]);
      const bf16x8 vf1 = *reinterpret_cast<const bf16x8*>(
          &Vl[buf][(nt * 16 + l16) * 64 + ((32 + g8 * 8) ^ cswz)]);
#pragma unroll
      for (int m = 0; m < 2; ++m) {
        o[m][nt] = __builtin_amdgcn_mfma_f32_16x16x32_bf16(pf[m][0], vf0, o[m][nt], 0, 0, 0);
        o[m][nt] = __builtin_amdgcn_mfma_f32_16x16x32_bf16(pf[m][1], vf1, o[m][nt], 0, 0, 0);
      }
    }

    wait_vm<0>();   // own prefetch DMAs retired; barrier makes all waves' visible
    block_bar();
  }

#pragma unroll
  for (int m = 0; m < 2; ++m) {
    f32x4 ld;
#pragma unroll
    for (int r = 0; r < 4; ++r) ld[r] = 1.0f / __shfl(li[m], g8 * 4 + r);
#pragma unroll
    for (int nt = 0; nt < 4; ++nt)
#pragma unroll
      for (int r = 0; r < 4; ++r) {
        const __bf16 v = (__bf16)(o[m][nt][r] * ld[r]);
        ctx[(rowB + q0 + m * 16 + g8 * 4 + r) * D_MODEL + colH + nt * 16 + l16] =
            __builtin_bit_cast(u16, v);
      }
  }
}

extern "C" void kernel_launch(void* const* d_in, const int* in_sizes, int n_in,
                              void* d_out, int out_size, void* d_ws, size_t ws_size,
                              hipStream_t stream) {
  const float* x   = (const float*)d_in[0];
  const float* wq  = (const float*)d_in[1];
  const float* wk  = (const float*)d_in[2];
  const float* wv  = (const float*)d_in[3];
  const float* wo  = (const float*)d_in[4];
  const float* bo  = (const float*)d_in[5];
  const float* l1g = (const float*)d_in[6];
  const float* l1b = (const float*)d_in[7];
  const float* l2g = (const float*)d_in[8];
  const float* l2b = (const float*)d_in[9];
  const float* w1  = (const float*)d_in[10];
  const float* b1  = (const float*)d_in[11];
  const float* w2  = (const float*)d_in[12];
  const float* b2  = (const float*)d_in[13];
  float* outp = (float*)d_out;

  uint8_t* ws = (uint8_t*)d_ws;
  const size_t MB = 1024 * 1024;
  u16* wqkvt = (u16*)(ws + 0 * MB);   // fused [3072][1024]: wq|wk|wv transposed
  u16* wqt   = wqkvt;
  u16* wkt   = (u16*)(ws + 2 * MB);
  u16* wvt   = (u16*)(ws + 4 * MB);
  u16* wot   = (u16*)(ws + 6 * MB);
  u16* w1t   = (u16*)(ws + 8 * MB);   // [4096][1024]
  u16* w2t   = (u16*)(ws + 16 * MB);  // [1024][4096]
  u16* xn    = (u16*)(ws + 24 * MB);  // [8192][1024]; reused as ctx after QKV
  u16* qbuf  = (u16*)(ws + 40 * MB);  // [8192][1024]; reused as h after attention
  u16* kbuf  = (u16*)(ws + 56 * MB);
  u16* vbufT = (u16*)(ws + 72 * MB);  // [4][1024][2048] transposed V
  u16* ctx   = xn;
  u16* hbuf  = qbuf;
  u16* ffh   = kbuf;                  // [8192][4096] overlays kbuf.. (vbufT dead by then)

  dim3 blk(256);
  dim3 blk5(512);

  // weights -> bf16 transposed; wq carries 0.125*log2(e) (attention scale + exp2 conv)
  wconv_kernel<<<dim3(32, 32), blk, 0, stream>>>(wq, wqt, 1024, 1024, 0.18033688011112042f);
  wconv_kernel<<<dim3(32, 32), blk, 0, stream>>>(wk, wkt, 1024, 1024, 1.0f);
  wconv_kernel<<<dim3(32, 32), blk, 0, stream>>>(wv, wvt, 1024, 1024, 1.0f);
  wconv_kernel<<<dim3(32, 32), blk, 0, stream>>>(wo, wot, 1024, 1024, 1.0f);
  wconv_kernel<<<dim3(128, 32), blk, 0, stream>>>(w1, w1t, 1024, 4096, 1.0f);
  wconv_kernel<<<dim3(32, 128), blk, 0, stream>>>(w2, w2t, 4096, 1024, 1.0f);

  // xn = LN1(x)
  ln_kernel<<<MROWS, blk, 0, stream>>>(x, xn, l1g, l1b);

  // fused QKV projection: [8192,1024] x [3072,1024]^T; q,k row-major, v transposed
  gemm8p_kernel<128, 4><<<dim3(12, 64), blk5, 0, stream>>>(
      xn, wqkvt, 3072, 1024, nullptr, nullptr, nullptr, qbuf, kbuf, vbufT);

  // ctx = softmax(QK^T/8) V
  attn_kernel<<<dim3(16, 64), blk, 0, stream>>>(qbuf, kbuf, vbufT, ctx);

  // xt = x + ctx@wo + bo   (-> d_out, f32)
  gemm8p_kernel<128, 1><<<dim3(4, 64), blk5, 0, stream>>>(
      ctx, wot, 1024, 1024, bo, x, outp, nullptr, nullptr, nullptr);

  // h = LN2(xt)
  ln_kernel<<<MROWS, blk, 0, stream>>>(outp, hbuf, l2g, l2b);

  // ffh = relu(h@w1 + b1)
  gemm8p_kernel<256, 2><<<dim3(16, 32), blk5, 0, stream>>>(
      hbuf, w1t, 4096, 1024, b1, nullptr, nullptr, ffh, nullptr, nullptr);

  // out = xt + ffh@w2 + b2  (in-place on d_out)
  gemm8p_kernel<128, 1><<<dim3(4, 64), blk5, 0, stream>>>(
      ffh, w2t, 1024, 4096, b2, outp, outp, nullptr, nullptr, nullptr);
}

// Round 7
// 548.224 us; speedup vs baseline: 1.2318x; 1.0091x over previous
//
#include <hip/hip_runtime.h>
#include <stdint.h>

typedef __attribute__((ext_vector_type(8))) __bf16 bf16x8;
typedef __attribute__((ext_vector_type(4))) __bf16 bf16x4;
typedef __attribute__((ext_vector_type(4))) float f32x4;
typedef unsigned short u16;

#define D_MODEL 1024
#define D_FF 4096
#define SEQ 2048
#define NHEAD 16
#define DH 64
#define MROWS 8192

__device__ __forceinline__ u16 f2bf(float f) {
  union { float f; unsigned u; } v; v.f = f;
  unsigned r = v.u + 0x7fffu + ((v.u >> 16) & 1u);
  return (u16)(r >> 16);
}

// async global->LDS, 16B per lane; lds dest wave-uniform base (+lane*16 implicit)
__device__ __forceinline__ void gload16(const u16* g, u16* l) {
  __builtin_amdgcn_global_load_lds((const __attribute__((address_space(1))) void*)(g),
                                   (__attribute__((address_space(3))) void*)(l),
                                   16, 0, 0);
}

// raw barrier (no vmcnt/lgkmcnt drain) + compiler memory fence both sides
__device__ __forceinline__ void block_bar() {
  asm volatile("" ::: "memory");
  __builtin_amdgcn_s_barrier();
  asm volatile("" ::: "memory");
}

template <int N>
__device__ __forceinline__ void wait_vm() {
  if constexpr (N == 6)      asm volatile("s_waitcnt vmcnt(6)" ::: "memory");
  else if constexpr (N == 4) asm volatile("s_waitcnt vmcnt(4)" ::: "memory");
  else if constexpr (N == 3) asm volatile("s_waitcnt vmcnt(3)" ::: "memory");
  else                       asm volatile("s_waitcnt vmcnt(0)" ::: "memory");
}

// ---------------- weight f32 [K][N] -> bf16 transposed [N][K] (optional scale) ----
__global__ __launch_bounds__(256)
void wconv_kernel(const float* __restrict__ W, u16* __restrict__ Wt, int K, int N,
                  float scale) {
  __shared__ u16 t[32][33];
  const int tid = threadIdx.x, tx = tid & 31, ty = tid >> 5;
  const int n0 = blockIdx.x * 32, k0 = blockIdx.y * 32;
#pragma unroll
  for (int i = 0; i < 4; ++i) {
    int k = ty + i * 8;
    t[k][tx] = f2bf(W[(size_t)(k0 + k) * N + n0 + tx] * scale);
  }
  __syncthreads();
#pragma unroll
  for (int i = 0; i < 4; ++i) {
    int n = ty + i * 8;
    Wt[(size_t)(n0 + n) * K + k0 + tx] = t[tx][n];
  }
}

// ---------------- layernorm: f32 [row][1024] -> bf16 ----------------
__global__ __launch_bounds__(256)
void ln_kernel(const float* __restrict__ x, u16* __restrict__ out,
               const float* __restrict__ g, const float* __restrict__ beta) {
  const int row = blockIdx.x, tid = threadIdx.x;
  const float4 v = reinterpret_cast<const float4*>(x + (size_t)row * D_MODEL)[tid];
  float s = v.x + v.y + v.z + v.w;
#pragma unroll
  for (int off = 32; off; off >>= 1) s += __shfl_down(s, off);
  __shared__ float red[8];
  if ((tid & 63) == 0) red[tid >> 6] = s;
  __syncthreads();
  const float mu = (red[0] + red[1] + red[2] + red[3]) * (1.0f / D_MODEL);
  const float dx = v.x - mu, dy = v.y - mu, dz = v.z - mu, dw = v.w - mu;
  float sq = dx * dx + dy * dy + dz * dz + dw * dw;
#pragma unroll
  for (int off = 32; off; off >>= 1) sq += __shfl_down(sq, off);
  if ((tid & 63) == 0) red[4 + (tid >> 6)] = sq;
  __syncthreads();
  const float var = (red[4] + red[5] + red[6] + red[7]) * (1.0f / D_MODEL);
  const float rs = rsqrtf(var + 1e-5f);
  const float4 gv = reinterpret_cast<const float4*>(g)[tid];
  const float4 bv = reinterpret_cast<const float4*>(beta)[tid];
  ushort4 ov;
  ov.x = f2bf(dx * rs * gv.x + bv.x);
  ov.y = f2bf(dy * rs * gv.y + bv.y);
  ov.z = f2bf(dz * rs * gv.z + bv.z);
  ov.w = f2bf(dw * rs * gv.w + bv.w);
  reinterpret_cast<ushort4*>(out + (size_t)row * D_MODEL)[tid] = ov;
}

// ======== phased TN GEMM: BMx256 tile, BK=64, 8 waves (2x4), dbuf, counted vmcnt ====
// BM=256: 8 phases / 2 K-tiles, MI=2 (m201 template, unchanged).
// BM=128: 4 phases / 2 K-tiles, MI=2 (16 MFMA/phase, half the barriers).
//   Stage plan (3/phase): p0:T+1{5,0,1} p1:T+2{2,3,4} p2:T+2{5,0,1} p3:T+3{2,3,4};
//   vmcnt(3) at p1/p3-end (vmcnt(0) when tail stops staging).
// EPI 1: C + bias[col] + res[idx] -> f32 outf (res may alias outf)
// EPI 2: relu(C + bias[col]) -> bf16 outb
// EPI 4: fused QKV: col seg 0 -> outb, 1 -> outb2 (row-major), 2 -> outb3 transposed
template <int BM, int EPI>
__global__ __launch_bounds__(512, 2)
void gemm8p_kernel(const u16* __restrict__ A, const u16* __restrict__ Bt,
                   int N, int K,
                   const float* __restrict__ bias,
                   const float* __restrict__ res,
                   float* __restrict__ outf, u16* __restrict__ outb,
                   u16* __restrict__ outb2, u16* __restrict__ outb3) {
  constexpr int WM = BM / 2;
  constexpr int MREP = WM / 16;       // 8 (BM=256) or 4 (BM=128)
  constexpr int MI = 2;               // mi per phase (both variants)
  constexpr int ACH = BM / 64;        // A chunks per K-tile
  constexpr int VN = (BM == 256) ? 6 : 3;
  __shared__ __align__(16) u16 Al[2][BM * 64];
  __shared__ __align__(16) u16 Bl[2][256 * 64];
  const int tid = threadIdx.x, lane = tid & 63, wave = tid >> 6;
  const int wr = wave >> 2, wc = wave & 3;
  const int l16 = lane & 15, g8 = lane >> 4;
  const int srw = lane >> 3;
  const int scl = ((lane & 7) ^ (lane >> 3)) * 8;
  const int swz = (l16 & 7) << 3;
  const int mBase = blockIdx.y * BM, nBase = blockIdx.x * 256;
  const int nt = K >> 6;

  f32x4 acc[MREP][4];
#pragma unroll
  for (int mi = 0; mi < MREP; ++mi)
#pragma unroll
    for (int nj = 0; nj < 4; ++nj) acc[mi][nj] = f32x4{0.f, 0.f, 0.f, 0.f};

  auto stageChunk = [&](int tile, int c) {
    if (tile >= nt) return;
    const int buf = tile & 1;
    if (c < ACH) {
      const int r0 = c * 64 + wave * 8;
      gload16(A + (size_t)(mBase + r0 + srw) * K + tile * 64 + scl,
              &Al[buf][r0 * 64]);
    } else {
      const int r0 = (c - ACH) * 64 + wave * 8;
      gload16(Bt + (size_t)(nBase + r0 + srw) * K + tile * 64 + scl,
              &Bl[buf][r0 * 64]);
    }
  };

  if constexpr (BM == 256) {
    constexpr int P0[8] = {4,5,6,7,0,2,1,3};
    constexpr int P1[6] = {4,5,6,7,0,2};
#pragma unroll
    for (int i = 0; i < 8; ++i) stageChunk(0, P0[i]);
#pragma unroll
    for (int i = 0; i < 6; ++i) stageChunk(1, P1[i]);
  } else {
    constexpr int P0[6] = {2,3,4,5,0,1};
    constexpr int P1[3] = {2,3,4};
#pragma unroll
    for (int i = 0; i < 6; ++i) stageChunk(0, P0[i]);
#pragma unroll
    for (int i = 0; i < 3; ++i) stageChunk(1, P1[i]);
  }
  wait_vm<VN>();
  block_bar();

  if constexpr (BM == 256) {
    constexpr int STO[16] = {1,1, 2,2, 2,2, 2,2, 2,2, 3,3, 3,3, 3,3};
    constexpr int STC[16] = {1,3, 4,5, 6,7, 0,2, 1,3, 4,5, 6,7, 0,2};
    for (int T = 0; T < nt; T += 2) {
      bf16x8 bfr[4][2];
#pragma unroll
      for (int p = 0; p < 8; ++p) {
        const int q = p & 3;
        const int buf = p >> 2;
        if (q == 0) {
#pragma unroll
          for (int nj = 0; nj < 4; ++nj)
#pragma unroll
            for (int ks = 0; ks < 2; ++ks) {
              const int rb = wc * 64 + nj * 16 + l16;
              bfr[nj][ks] = *reinterpret_cast<const bf16x8*>(
                  &Bl[buf][rb * 64 + ((ks * 32 + g8 * 8) ^ swz)]);
            }
        }
        bf16x8 af[MI][2];
#pragma unroll
        for (int i = 0; i < MI; ++i)
#pragma unroll
          for (int ks = 0; ks < 2; ++ks) {
            const int ra = wr * WM + (q * MI + i) * 16 + l16;
            af[i][ks] = *reinterpret_cast<const bf16x8*>(
                &Al[buf][ra * 64 + ((ks * 32 + g8 * 8) ^ swz)]);
          }
        stageChunk(T + STO[2 * p], STC[2 * p]);
        stageChunk(T + STO[2 * p + 1], STC[2 * p + 1]);
        block_bar();
        __builtin_amdgcn_s_setprio(1);
#pragma unroll
        for (int i = 0; i < MI; ++i)
#pragma unroll
          for (int nj = 0; nj < 4; ++nj)
#pragma unroll
            for (int ks = 0; ks < 2; ++ks)
              acc[q * MI + i][nj] = __builtin_amdgcn_mfma_f32_16x16x32_bf16(
                  af[i][ks], bfr[nj][ks], acc[q * MI + i][nj], 0, 0, 0);
        __builtin_amdgcn_s_setprio(0);
        if (p == 3) {
          if (T + 2 < nt) wait_vm<VN>(); else wait_vm<0>();
        } else if (p == 7) {
          wait_vm<VN>();
        }
        block_bar();
      }
    }
  } else {
    // 4-phase / 2-tile, MI=2
    constexpr int STO[12] = {1,1,1, 2,2,2, 2,2,2, 3,3,3};
    constexpr int STC[12] = {5,0,1, 2,3,4, 5,0,1, 2,3,4};
    for (int T = 0; T < nt; T += 2) {
      bf16x8 bfr[4][2];
#pragma unroll
      for (int p = 0; p < 4; ++p) {
        const int q = p & 1;
        const int buf = p >> 1;
        if (q == 0) {
#pragma unroll
          for (int nj = 0; nj < 4; ++nj)
#pragma unroll
            for (int ks = 0; ks < 2; ++ks) {
              const int rb = wc * 64 + nj * 16 + l16;
              bfr[nj][ks] = *reinterpret_cast<const bf16x8*>(
                  &Bl[buf][rb * 64 + ((ks * 32 + g8 * 8) ^ swz)]);
            }
        }
        bf16x8 af[MI][2];
#pragma unroll
        for (int i = 0; i < MI; ++i)
#pragma unroll
          for (int ks = 0; ks < 2; ++ks) {
            const int ra = wr * WM + (q * MI + i) * 16 + l16;
            af[i][ks] = *reinterpret_cast<const bf16x8*>(
                &Al[buf][ra * 64 + ((ks * 32 + g8 * 8) ^ swz)]);
          }
        stageChunk(T + STO[3 * p], STC[3 * p]);
        stageChunk(T + STO[3 * p + 1], STC[3 * p + 1]);
        stageChunk(T + STO[3 * p + 2], STC[3 * p + 2]);
        block_bar();
        __builtin_amdgcn_s_setprio(1);
#pragma unroll
        for (int i = 0; i < MI; ++i)
#pragma unroll
          for (int nj = 0; nj < 4; ++nj)
#pragma unroll
            for (int ks = 0; ks < 2; ++ks)
              acc[q * MI + i][nj] = __builtin_amdgcn_mfma_f32_16x16x32_bf16(
                  af[i][ks], bfr[nj][ks], acc[q * MI + i][nj], 0, 0, 0);
        __builtin_amdgcn_s_setprio(0);
        if (p == 1) {
          if (T + 2 < nt) wait_vm<VN>(); else wait_vm<0>();
        } else if (p == 3) {
          if (T + 3 < nt) wait_vm<VN>(); else wait_vm<0>();
        }
        block_bar();
      }
    }
  }

#pragma unroll
  for (int mi = 0; mi < MREP; ++mi)
#pragma unroll
    for (int nj = 0; nj < 4; ++nj) {
      const int colB = wc * 64 + nj * 16 + l16;
      const int row0 = mBase + wr * WM + mi * 16 + g8 * 4;
      if (EPI == 4) {
        const int seg = nBase >> 10;
        const int c = (nBase & 1023) + colB;
        if (seg == 2) {
          const int bi = row0 >> 11, s = row0 & 2047;
          ushort4 pk;
          pk.x = f2bf(acc[mi][nj][0]);
          pk.y = f2bf(acc[mi][nj][1]);
          pk.z = f2bf(acc[mi][nj][2]);
          pk.w = f2bf(acc[mi][nj][3]);
          *reinterpret_cast<ushort4*>(outb3 + ((size_t)(bi << 10) + c) * SEQ + s) = pk;
        } else {
          u16* o = (seg == 0) ? outb : outb2;
#pragma unroll
          for (int r = 0; r < 4; ++r)
            o[(size_t)(row0 + r) * D_MODEL + c] = f2bf(acc[mi][nj][r]);
        }
      } else {
        const int col = nBase + colB;
        const float bv = bias[col];
#pragma unroll
        for (int r = 0; r < 4; ++r) {
          const size_t idx = (size_t)(row0 + r) * N + col;
          const float vv = acc[mi][nj][r];
          if (EPI == 1) {
            outf[idx] = vv + bv + res[idx];
          } else {
            const float tv = vv + bv;
            outb[idx] = f2bf(tv > 0.f ? tv : 0.f);
          }
        }
      }
    }
}

// ---------------- flash attention: async dbuf KV, exp2, defer-max (T13) ----------
// 4 waves x 32 q-rows, KV tile 64. Swapped QK^T: lane holds q = l16, kv = kt*16+g8*4+r.
// qb pre-scaled by 0.125*log2(e) (folded into wq) -> softmax uses exp2 directly.
// Defer-max: skip alpha/o-rescale when __all(pmax - mi <= 8) -> P bounded by 2^8.
// vb is V^T per batch: vb[(b*1024 + h*64 + d)*2048 + s].
__global__ __launch_bounds__(256)
void attn_kernel(const u16* __restrict__ qb, const u16* __restrict__ kb,
                 const u16* __restrict__ vb, u16* __restrict__ ctx) {
  __shared__ __align__(16) u16 Kl[2][64 * 64];
  __shared__ __align__(16) u16 Vl[2][64 * 64];   // V^T tile: Vl[d][t]
  __shared__ __align__(16) u16 Pl[4][32 * 64];   // per-wave P: [q 32][kv 64]
  const int tid = threadIdx.x;
  const int lane = tid & 63, wave = tid >> 6, g8 = lane >> 4, l16 = lane & 15;
  const int b = blockIdx.y >> 4, h = blockIdx.y & 15;
  const int q0 = blockIdx.x * 128 + wave * 32;
  const size_t rowB = (size_t)b * SEQ;
  const int colH = h * DH;
  const size_t vtBase = (size_t)(b * 1024 + colH) * SEQ;
  const int srw = lane >> 3;
  const int scl = ((lane & 7) ^ (lane >> 3)) * 8;
  const int cswz = (l16 & 7) * 8;

  bf16x8 qf[2][2];
#pragma unroll
  for (int m = 0; m < 2; ++m)
#pragma unroll
    for (int ks = 0; ks < 2; ++ks)
      qf[m][ks] = *reinterpret_cast<const bf16x8*>(
          qb + (rowB + q0 + m * 16 + l16) * D_MODEL + colH + ks * 32 + g8 * 8);

  float mi[2] = {-1e30f, -1e30f}, li[2] = {0.f, 0.f};
  f32x4 o[2][4];
#pragma unroll
  for (int m = 0; m < 2; ++m)
#pragma unroll
    for (int nt = 0; nt < 4; ++nt) o[m][nt] = f32x4{0.f, 0.f, 0.f, 0.f};

  auto stageKV = [&](int t0, int buf) {
    if (t0 >= SEQ) return;
#pragma unroll
    for (int i = 0; i < 2; ++i) {
      const int r0 = wave * 16 + i * 8;
      gload16(kb + (rowB + t0 + r0 + srw) * D_MODEL + colH + scl, &Kl[buf][r0 * 64]);
      gload16(vb + vtBase + (size_t)(r0 + srw) * SEQ + t0 + scl, &Vl[buf][r0 * 64]);
    }
  };

  stageKV(0, 0);
  wait_vm<0>();
  block_bar();

  int buf = 0;
  for (int t0 = 0; t0 < SEQ; t0 += 64, buf ^= 1) {
    stageKV(t0 + 64, buf ^ 1);

    f32x4 st[2][4];
#pragma unroll
    for (int m = 0; m < 2; ++m)
#pragma unroll
      for (int kt = 0; kt < 4; ++kt) st[m][kt] = f32x4{0.f, 0.f, 0.f, 0.f};
#pragma unroll
    for (int kt = 0; kt < 4; ++kt) {
      const bf16x8 kf0 = *reinterpret_cast<const bf16x8*>(
          &Kl[buf][(kt * 16 + l16) * 64 + ((g8 * 8) ^ cswz)]);
      const bf16x8 kf1 = *reinterpret_cast<const bf16x8*>(
          &Kl[buf][(kt * 16 + l16) * 64 + ((32 + g8 * 8) ^ cswz)]);
#pragma unroll
      for (int m = 0; m < 2; ++m) {
        st[m][kt] = __builtin_amdgcn_mfma_f32_16x16x32_bf16(kf0, qf[m][0], st[m][kt], 0, 0, 0);
        st[m][kt] = __builtin_amdgcn_mfma_f32_16x16x32_bf16(kf1, qf[m][1], st[m][kt], 0, 0, 0);
      }
    }

    float alpha[2];
    bool dor[2];
#pragma unroll
    for (int m = 0; m < 2; ++m) {
      float pmax = st[m][0][0];
#pragma unroll
      for (int kt = 0; kt < 4; ++kt)
#pragma unroll
        for (int r = 0; r < 4; ++r) pmax = fmaxf(pmax, st[m][kt][r]);
      pmax = fmaxf(pmax, __shfl_xor(pmax, 16));
      pmax = fmaxf(pmax, __shfl_xor(pmax, 32));
      dor[m] = !__all(pmax - mi[m] <= 8.0f);
      alpha[m] = 1.0f;
      if (dor[m]) {
        const float mnew = fmaxf(mi[m], pmax);
        alpha[m] = __builtin_amdgcn_exp2f(mi[m] - mnew);
        mi[m] = mnew;
      }
      float sum = 0.f;
#pragma unroll
      for (int kt = 0; kt < 4; ++kt) {
        bf16x4 pk;
#pragma unroll
        for (int r = 0; r < 4; ++r) {
          const float p = __builtin_amdgcn_exp2f(st[m][kt][r] - mi[m]);
          sum += p;
          pk[r] = (__bf16)p;
        }
        const int row = m * 16 + l16;
        *reinterpret_cast<bf16x4*>(
            &Pl[wave][row * 64 + ((kt * 16 + g8 * 4) ^ cswz)]) = pk;
      }
      sum += __shfl_xor(sum, 16);
      sum += __shfl_xor(sum, 32);
      li[m] = li[m] * alpha[m] + sum;
    }

#pragma unroll
    for (int m = 0; m < 2; ++m) {
      if (dor[m]) {
        f32x4 al;
#pragma unroll
        for (int r = 0; r < 4; ++r) al[r] = __shfl(alpha[m], g8 * 4 + r);
#pragma unroll
        for (int nt = 0; nt < 4; ++nt) {
          f32x4 t = o[m][nt];
          t[0] *= al[0]; t[1] *= al[1]; t[2] *= al[2]; t[3] *= al[3];
          o[m][nt] = t;
        }
      }
    }

    bf16x8 pf[2][2];
#pragma unroll
    for (int m = 0; m < 2; ++m)
#pragma unroll
      for (int ks = 0; ks < 2; ++ks)
        pf[m][ks] = *reinterpret_cast<const bf16x8*>(
            &Pl[wave][(m * 16 + l16) * 64 + ((ks * 32 + g8 * 8) ^ cswz)]);
#pragma unroll
    for (int nt = 0; nt < 4; ++nt) {
      const bf16x8 vf0 = *reinterpret_cast<const bf16x8*>(
          &Vl[buf][(nt * 16 + l16) * 64 + ((g8 * 8) ^ cswz)]);
      const bf16x8 vf1 = *reinterpret_cast<const bf16x8*>(
          &Vl[buf][(nt * 16 + l16) * 64 + ((32 + g8 * 8) ^ cswz)]);
#pragma unroll
      for (int m = 0; m < 2; ++m) {
        o[m][nt] = __builtin_amdgcn_mfma_f32_16x16x32_bf16(pf[m][0], vf0, o[m][nt], 0, 0, 0);
        o[m][nt] = __builtin_amdgcn_mfma_f32_16x16x32_bf16(pf[m][1], vf1, o[m][nt], 0, 0, 0);
      }
    }

    wait_vm<0>();
    block_bar();
  }

#pragma unroll
  for (int m = 0; m < 2; ++m) {
    f32x4 ld;
#pragma unroll
    for (int r = 0; r < 4; ++r) ld[r] = 1.0f / __shfl(li[m], g8 * 4 + r);
#pragma unroll
    for (int nt = 0; nt < 4; ++nt)
#pragma unroll
      for (int r = 0; r < 4; ++r) {
        const __bf16 v = (__bf16)(o[m][nt][r] * ld[r]);
        ctx[(rowB + q0 + m * 16 + g8 * 4 + r) * D_MODEL + colH + nt * 16 + l16] =
            __builtin_bit_cast(u16, v);
      }
  }
}

extern "C" void kernel_launch(void* const* d_in, const int* in_sizes, int n_in,
                              void* d_out, int out_size, void* d_ws, size_t ws_size,
                              hipStream_t stream) {
  const float* x   = (const float*)d_in[0];
  const float* wq  = (const float*)d_in[1];
  const float* wk  = (const float*)d_in[2];
  const float* wv  = (const float*)d_in[3];
  const float* wo  = (const float*)d_in[4];
  const float* bo  = (const float*)d_in[5];
  const float* l1g = (const float*)d_in[6];
  const float* l1b = (const float*)d_in[7];
  const float* l2g = (const float*)d_in[8];
  const float* l2b = (const float*)d_in[9];
  const float* w1  = (const float*)d_in[10];
  const float* b1  = (const float*)d_in[11];
  const float* w2  = (const float*)d_in[12];
  const float* b2  = (const float*)d_in[13];
  float* outp = (float*)d_out;

  uint8_t* ws = (uint8_t*)d_ws;
  const size_t MB = 1024 * 1024;
  u16* wqkvt = (u16*)(ws + 0 * MB);   // fused [3072][1024]: wq|wk|wv transposed
  u16* wqt   = wqkvt;
  u16* wkt   = (u16*)(ws + 2 * MB);
  u16* wvt   = (u16*)(ws + 4 * MB);
  u16* wot   = (u16*)(ws + 6 * MB);
  u16* w1t   = (u16*)(ws + 8 * MB);   // [4096][1024]
  u16* w2t   = (u16*)(ws + 16 * MB);  // [1024][4096]
  u16* xn    = (u16*)(ws + 24 * MB);  // [8192][1024]; reused as ctx after QKV
  u16* qbuf  = (u16*)(ws + 40 * MB);  // [8192][1024]; reused as h after attention
  u16* kbuf  = (u16*)(ws + 56 * MB);
  u16* vbufT = (u16*)(ws + 72 * MB);  // [4][1024][2048] transposed V
  u16* ctx   = xn;
  u16* hbuf  = qbuf;
  u16* ffh   = kbuf;                  // [8192][4096] overlays kbuf.. (vbufT dead by then)

  dim3 blk(256);
  dim3 blk5(512);

  // weights -> bf16 transposed; wq carries 0.125*log2(e) (attention scale + exp2 conv)
  wconv_kernel<<<dim3(32, 32), blk, 0, stream>>>(wq, wqt, 1024, 1024, 0.18033688011112042f);
  wconv_kernel<<<dim3(32, 32), blk, 0, stream>>>(wk, wkt, 1024, 1024, 1.0f);
  wconv_kernel<<<dim3(32, 32), blk, 0, stream>>>(wv, wvt, 1024, 1024, 1.0f);
  wconv_kernel<<<dim3(32, 32), blk, 0, stream>>>(wo, wot, 1024, 1024, 1.0f);
  wconv_kernel<<<dim3(128, 32), blk, 0, stream>>>(w1, w1t, 1024, 4096, 1.0f);
  wconv_kernel<<<dim3(32, 128), blk, 0, stream>>>(w2, w2t, 4096, 1024, 1.0f);

  // xn = LN1(x)
  ln_kernel<<<MROWS, blk, 0, stream>>>(x, xn, l1g, l1b);

  // fused QKV projection: [8192,1024] x [3072,1024]^T; q,k row-major, v transposed
  gemm8p_kernel<128, 4><<<dim3(12, 64), blk5, 0, stream>>>(
      xn, wqkvt, 3072, 1024, nullptr, nullptr, nullptr, qbuf, kbuf, vbufT);

  // ctx = softmax(QK^T/8) V
  attn_kernel<<<dim3(16, 64), blk, 0, stream>>>(qbuf, kbuf, vbufT, ctx);

  // xt = x + ctx@wo + bo   (-> d_out, f32)
  gemm8p_kernel<128, 1><<<dim3(4, 64), blk5, 0, stream>>>(
      ctx, wot, 1024, 1024, bo, x, outp, nullptr, nullptr, nullptr);

  // h = LN2(xt)
  ln_kernel<<<MROWS, blk, 0, stream>>>(outp, hbuf, l2g, l2b);

  // ffh = relu(h@w1 + b1)
  gemm8p_kernel<256, 2><<<dim3(16, 32), blk5, 0, stream>>>(
      hbuf, w1t, 4096, 1024, b1, nullptr, nullptr, ffh, nullptr, nullptr);

  // out = xt + ffh@w2 + b2  (in-place on d_out)
  gemm8p_kernel<128, 1><<<dim3(4, 64), blk5, 0, stream>>>(
      ffh, w2t, 1024, 4096, b2, outp, outp, nullptr, nullptr, nullptr);
}